// Round 10
// baseline (90.146 us; speedup 1.0000x reference)
//
#include <hip/hip_runtime.h>
#include <math.h>

#define B_ 16
#define N_ 1024
#define F_ 2048
#define FPB 64            // freqs per block == lanes per wave
#define SLICES 16         // one N-slice per wave; 1024-thread blocks
#define NS (N_ / SLICES)  // 64 samples per slice
#define NC (NS / 4)       // 16 float4 chunks per slice

typedef float v2f __attribute__((ext_vector_type(2)));

// ROUND 10: DIAGNOSTIC. Identical math to round 9, but the accumulation
// loop runs TWICE (bit-exact: rep1 restarts from an opaque zero and its
// results -- identical bits to rep0's -- feed the output). Purpose: push
// the power kernel above the 40us harness fill kernels so rocprof's top-5
// finally reports its VALUBusy/Occupancy/VGPR, and measure its true cost
// as dur(2x) - dur(1x). Output must be bit-identical to round 9
// (absmax exactly 0.0078125).
__global__ __launch_bounds__(1024, 8) void ls_power_kernel(
    const float* __restrict__ t,
    const float* __restrict__ y,
    const float* __restrict__ mask,
    const float* __restrict__ freqs,
    float* __restrict__ p_out)
{
    const int tid   = threadIdx.x;
    const int fi    = tid & (FPB - 1);
    const int slice = tid >> 6;               // 0..15, wave index
    const int b     = blockIdx.y;
    const int f     = blockIdx.x * FPB + fi;

    const float freq = freqs[f];
    const v2f  fq2  = {freq, freq};
    const v2f  onev = {1.0f, 1.0f};
    const v2f  ntwo = {-2.0f, -2.0f};

    // ---- stage this batch's t/y/mask into LDS (12 KB) ----
    __shared__ float4 sh[3 * (N_ / 4)];       // [0:256) t | [256:512) y | [512:768) m
    if (tid < 3 * (N_ / 4)) {
        const int a = tid >> 8;               // which array
        const int i = tid & (N_ / 4 - 1);     // float4 index within row
        const float4* __restrict__ src =
            (a == 0) ? (const float4*)t : (a == 1) ? (const float4*)y
                                                   : (const float4*)mask;
        sh[tid] = src[b * (N_ / 4) + i];
    }

    __shared__ float red[SLICES][7][FPB];
    __syncthreads();

    const float4* __restrict__ sh_t = sh;
    const float4* __restrict__ sh_y = sh + (N_ / 4);
    const float4* __restrict__ sh_m = sh + 2 * (N_ / 4);
    const int c0 = slice * NC;                // wave-uniform chunk base

    v2f S = {0.f, 0.f}, C = S, S2 = S, C2 = S, Sy = S, Cy = S, M2 = S;

    auto pair = [&](float ta, float tb, float ya, float yb, float ma, float mb) {
        v2f tn = {ta, tb}, yn = {ya, yb}, mn = {ma, mb};
        v2f ph = fq2 * tn;                                  // pk_mul (revolutions)
        v2f pe = __builtin_elementwise_fma(fq2, tn, -ph);   // pk_fma, exact resid
        v2f fr = {__builtin_amdgcn_fractf(ph.x),
                  __builtin_amdgcn_fractf(ph.y)};
        v2f r  = fr + pe;                                   // pk_add
        v2f s0 = {__builtin_amdgcn_sinf(r.x), __builtin_amdgcn_sinf(r.y)};
        v2f c0v = {__builtin_amdgcn_cosf(r.x), __builtin_amdgcn_cosf(r.y)};
        v2f t1 = s0 * c0v;
        v2f s2v = t1 + t1;                                  // sin(2wt)
        v2f w  = s0 * s0;
        v2f c2v = __builtin_elementwise_fma(w, ntwo, onev); // cos(2wt)
        v2f m2v = mn * mn;
        v2f ymv = yn * mn;
        S  = __builtin_elementwise_fma(s2v, mn,  S);
        C  = __builtin_elementwise_fma(c2v, mn,  C);
        S2 = __builtin_elementwise_fma(s2v, m2v, S2);
        C2 = __builtin_elementwise_fma(c2v, m2v, C2);
        Sy = __builtin_elementwise_fma(s0,  ymv, Sy);
        Cy = __builtin_elementwise_fma(c0v, ymv, Cy);
        M2 = M2 + m2v;
    };

    // ---- diagnostic rep loop: run the accumulation twice, bit-exactly ----
#pragma unroll 1
    for (int rep = 0; rep < 2; ++rep) {
        // opaque zero: compiler cannot prove rep1 == rep0, so no CSE/merge
        float z;
        asm volatile("v_mov_b32 %0, 0" : "=v"(z));
        v2f Zv = {z, z};
        S = Zv; C = Zv; S2 = Zv; C2 = Zv; Sy = Zv; Cy = Zv; M2 = Zv;

#pragma unroll 2
        for (int ch = 0; ch < NC; ++ch) {
            float4 tv = sh_t[c0 + ch];
            float4 yv = sh_y[c0 + ch];
            float4 mv = sh_m[c0 + ch];
            pair(tv.x, tv.y, yv.x, yv.y, mv.x, mv.y);
            pair(tv.z, tv.w, yv.z, yv.w, mv.z, mv.w);
        }

        // consume rep0's results so it isn't dead code (rule #17)
        asm volatile("" :: "v"(S.x),  "v"(S.y),  "v"(C.x),  "v"(C.y),
                           "v"(S2.x), "v"(S2.y), "v"(C2.x), "v"(C2.y),
                           "v"(Sy.x), "v"(Sy.y), "v"(Cy.x), "v"(Cy.y),
                           "v"(M2.x), "v"(M2.y));
    }

    red[slice][0][fi] = S.x  + S.y;
    red[slice][1][fi] = C.x  + C.y;
    red[slice][2][fi] = S2.x + S2.y;
    red[slice][3][fi] = C2.x + C2.y;
    red[slice][4][fi] = Sy.x + Sy.y;
    red[slice][5][fi] = Cy.x + Cy.y;
    red[slice][6][fi] = M2.x + M2.y;
    __syncthreads();

    if (slice == 0) {
        float rS = 0.f, rC = 0.f, rS2 = 0.f, rC2 = 0.f, rSy = 0.f, rCy = 0.f, rM2 = 0.f;
#pragma unroll
        for (int k = 0; k < SLICES; ++k) {
            rS  += red[k][0][fi];
            rC  += red[k][1][fi];
            rS2 += red[k][2][fi];
            rC2 += red[k][3][fi];
            rSy += red[k][4][fi];
            rCy += red[k][5][fi];
            rM2 += red[k][6][fi];
        }

        float h      = sqrtf(__builtin_fmaf(rS, rS, rC * rC)) + 1e-30f;
        float cos2p  = rC / h;
        float sin2p  = rS / h;
        float cosp   = sqrtf(0.5f * (1.0f + cos2p));
        float sinp   = __builtin_copysignf(sqrtf(0.5f * (1.0f - cos2p)), rS);

        float YC = cosp * rCy + sinp * rSy;
        float YS = cosp * rSy - sinp * rCy;
        float cross = cos2p * rC2 + sin2p * rS2;
        float CCd = 0.5f * (rM2 + cross);
        float SSd = 0.5f * (rM2 - cross);

        float p_cos = (YC * YC) / (CCd + 1e-10f);
        float p_sin = (YS * YS) / (SSd + 1e-10f);
        float p = 0.5f * (p_cos + p_sin);

        // fap = 1 - (1 - exp(-p))^2048 -- keep the naive fp32 path (matches np)
        float fap = 1.0f - powf(1.0f - expf(-p), 2048.0f);
        p = p * (1.0f / (fap + 1e-5f));

        p_out[b * F_ + f] = p;
    }
}

// One block per batch: trapezoid integral over F, then in-place normalize.
__global__ __launch_bounds__(256) void ls_norm_kernel(
    const float* __restrict__ freqs,
    float* __restrict__ p)   // d_out, in place
{
    const int b   = blockIdx.x;
    const int tid = threadIdx.x;
    float* __restrict__ pb = p + b * F_;

    float local = 0.0f;
    for (int j = tid; j < F_ - 1; j += 256) {
        float df = freqs[j + 1] - freqs[j];
        local += 0.5f * (pb[j] + pb[j + 1]) * df;
    }

    __shared__ float sred[256];
    sred[tid] = local;
    __syncthreads();
    for (int o = 128; o > 0; o >>= 1) {
        if (tid < o) sred[tid] += sred[tid + o];
        __syncthreads();
    }
    const float integral = sred[0] + 1e-10f;

#pragma unroll
    for (int k = 0; k < F_ / 256; ++k) {
        int j = tid + k * 256;
        pb[j] = pb[j] / integral;
    }
}

extern "C" void kernel_launch(void* const* d_in, const int* in_sizes, int n_in,
                              void* d_out, int out_size, void* d_ws, size_t ws_size,
                              hipStream_t stream) {
    const float* t     = (const float*)d_in[0];
    const float* y     = (const float*)d_in[1];
    const float* mask  = (const float*)d_in[2];
    const float* freqs = (const float*)d_in[3];
    float* out = (float*)d_out;

    dim3 grid1(F_ / FPB, B_);   // 32 x 16 = 512 blocks x 1024 threads
    ls_power_kernel<<<grid1, 1024, 0, stream>>>(t, y, mask, freqs, out);
    ls_norm_kernel<<<B_, 256, 0, stream>>>(freqs, out);
}

// Round 11
// 81.881 us; speedup vs baseline: 1.1009x; 1.1009x over previous
//
#include <hip/hip_runtime.h>
#include <math.h>

#define B_ 16
#define N_ 1024
#define F_ 2048
#define FPB 64            // freqs per block == lanes per wave
#define SLICES 16         // one N-slice per wave; 1024-thread blocks
#define NS (N_ / SLICES)  // 64 samples per slice
#define NC (NS / 4)       // 16 float4 chunks per slice

typedef float v2f __attribute__((ext_vector_type(2)));

// Single-pass Lomb-Scargle (Press & Rybicki), packed-FP32 inner loop.
// ROUND 11 change: the separate norm kernel is FUSED here via a
// last-block-per-batch atomic. d_ws[0..15] are per-batch counters zeroed by
// hipMemsetAsync before launch; after a block stores its 64 p values its
// slice-0 wave does __threadfence (release: vmem drain + L2 writeback to
// the coherence point) + atomicAdd(cnt[b]); the 32nd block acquires
// (__threadfence -> L1/L2 inv, ordered before loads by the barrier) and
// normalizes p[b,:] with all 1024 threads. Removes one kernel launch and
// one graph node from the timed window.
//
// Accumulation math identical to rounds 9/10 (absmax anchor 0.0078):
//   s0=sin(wt), c0=cos(wt) once per sample (hardware trig in revolutions,
//   Dekker split for ~1ulp fractional revolution);
//   sin2wt = 2 s0 c0, cos2wt = 1-2 s0^2;
//   S,C (mask^1) feed tau; S2,C2,M2 (mask^2) feed denominators;
//   epilogue uses half-angle rotation -- no trig.
__global__ __launch_bounds__(1024, 8) void ls_power_kernel(
    const float* __restrict__ t,
    const float* __restrict__ y,
    const float* __restrict__ mask,
    const float* __restrict__ freqs,
    float* __restrict__ p_out,
    unsigned* __restrict__ cnt)
{
    const int tid   = threadIdx.x;
    const int fi    = tid & (FPB - 1);
    const int slice = tid >> 6;               // 0..15, wave index
    const int b     = blockIdx.y;
    const int f     = blockIdx.x * FPB + fi;

    const float freq = freqs[f];
    const v2f  fq2  = {freq, freq};
    const v2f  onev = {1.0f, 1.0f};
    const v2f  ntwo = {-2.0f, -2.0f};

    // ---- stage this batch's t/y/mask into LDS (12 KB) ----
    __shared__ float4 sh[3 * (N_ / 4)];       // [0:256) t | [256:512) y | [512:768) m
    if (tid < 3 * (N_ / 4)) {
        const int a = tid >> 8;               // which array
        const int i = tid & (N_ / 4 - 1);     // float4 index within row
        const float4* __restrict__ src =
            (a == 0) ? (const float4*)t : (a == 1) ? (const float4*)y
                                                   : (const float4*)mask;
        sh[tid] = src[b * (N_ / 4) + i];
    }

    __shared__ float red[SLICES][7][FPB];
    __shared__ float sred[16];
    __shared__ int   sh_last;
    __syncthreads();

    const float4* __restrict__ sh_t = sh;
    const float4* __restrict__ sh_y = sh + (N_ / 4);
    const float4* __restrict__ sh_m = sh + 2 * (N_ / 4);
    const int c0 = slice * NC;                // wave-uniform chunk base

    v2f S = {0.f, 0.f}, C = S, S2 = S, C2 = S, Sy = S, Cy = S, M2 = S;

    auto pair = [&](float ta, float tb, float ya, float yb, float ma, float mb) {
        v2f tn = {ta, tb}, yn = {ya, yb}, mn = {ma, mb};
        v2f ph = fq2 * tn;                                  // pk_mul (revolutions)
        v2f pe = __builtin_elementwise_fma(fq2, tn, -ph);   // pk_fma, exact resid
        v2f fr = {__builtin_amdgcn_fractf(ph.x),
                  __builtin_amdgcn_fractf(ph.y)};
        v2f r  = fr + pe;                                   // pk_add
        v2f s0 = {__builtin_amdgcn_sinf(r.x), __builtin_amdgcn_sinf(r.y)};
        v2f c0v = {__builtin_amdgcn_cosf(r.x), __builtin_amdgcn_cosf(r.y)};
        v2f t1 = s0 * c0v;
        v2f s2v = t1 + t1;                                  // sin(2wt)
        v2f w  = s0 * s0;
        v2f c2v = __builtin_elementwise_fma(w, ntwo, onev); // cos(2wt)
        v2f m2v = mn * mn;
        v2f ymv = yn * mn;
        S  = __builtin_elementwise_fma(s2v, mn,  S);
        C  = __builtin_elementwise_fma(c2v, mn,  C);
        S2 = __builtin_elementwise_fma(s2v, m2v, S2);
        C2 = __builtin_elementwise_fma(c2v, m2v, C2);
        Sy = __builtin_elementwise_fma(s0,  ymv, Sy);
        Cy = __builtin_elementwise_fma(c0v, ymv, Cy);
        M2 = M2 + m2v;
    };

#pragma unroll 2
    for (int ch = 0; ch < NC; ++ch) {
        float4 tv = sh_t[c0 + ch];
        float4 yv = sh_y[c0 + ch];
        float4 mv = sh_m[c0 + ch];
        pair(tv.x, tv.y, yv.x, yv.y, mv.x, mv.y);
        pair(tv.z, tv.w, yv.z, yv.w, mv.z, mv.w);
    }

    red[slice][0][fi] = S.x  + S.y;
    red[slice][1][fi] = C.x  + C.y;
    red[slice][2][fi] = S2.x + S2.y;
    red[slice][3][fi] = C2.x + C2.y;
    red[slice][4][fi] = Sy.x + Sy.y;
    red[slice][5][fi] = Cy.x + Cy.y;
    red[slice][6][fi] = M2.x + M2.y;
    __syncthreads();

    if (slice == 0) {
        float rS = 0.f, rC = 0.f, rS2 = 0.f, rC2 = 0.f, rSy = 0.f, rCy = 0.f, rM2 = 0.f;
#pragma unroll
        for (int k = 0; k < SLICES; ++k) {
            rS  += red[k][0][fi];
            rC  += red[k][1][fi];
            rS2 += red[k][2][fi];
            rC2 += red[k][3][fi];
            rSy += red[k][4][fi];
            rCy += red[k][5][fi];
            rM2 += red[k][6][fi];
        }

        float h      = sqrtf(__builtin_fmaf(rS, rS, rC * rC)) + 1e-30f;
        float cos2p  = rC / h;
        float sin2p  = rS / h;
        float cosp   = sqrtf(0.5f * (1.0f + cos2p));
        float sinp   = __builtin_copysignf(sqrtf(0.5f * (1.0f - cos2p)), rS);

        float YC = cosp * rCy + sinp * rSy;
        float YS = cosp * rSy - sinp * rCy;
        float cross = cos2p * rC2 + sin2p * rS2;
        float CCd = 0.5f * (rM2 + cross);
        float SSd = 0.5f * (rM2 - cross);

        float p_cos = (YC * YC) / (CCd + 1e-10f);
        float p_sin = (YS * YS) / (SSd + 1e-10f);
        float p = 0.5f * (p_cos + p_sin);

        // fap = 1 - (1 - exp(-p))^2048 -- keep the naive fp32 path (matches np)
        float fap = 1.0f - powf(1.0f - expf(-p), 2048.0f);
        p = p * (1.0f / (fap + 1e-5f));

        p_out[b * F_ + f] = p;
    }

    // ---- last-block-per-batch fused normalize ----
    if (tid == 0) {
        __threadfence();                       // release: our 64 p stores -> coherence point
        unsigned old = atomicAdd(cnt + b, 1u);
        int last = (old == 32u * (F_ / FPB) / 32u - 1u);   // == 31
        sh_last = last;
        if (last) __threadfence();             // acquire: inv L1/L2 before re-reading p
    }
    __syncthreads();

    if (sh_last) {
        float* __restrict__ pb = p_out + b * F_;
        float local = 0.0f;
#pragma unroll
        for (int j = tid; j < F_ - 1; j += 1024) {   // 2 iters per thread
            float df = freqs[j + 1] - freqs[j];
            local += 0.5f * (pb[j] + pb[j + 1]) * df;
        }
        // wave reduce (64 lanes)
#pragma unroll
        for (int o = 32; o > 0; o >>= 1) local += __shfl_down(local, o);
        const int lane = tid & 63, wid = tid >> 6;
        if (lane == 0) sred[wid] = local;
        __syncthreads();
        if (wid == 0) {
            float v = (lane < 16) ? sred[lane] : 0.0f;
#pragma unroll
            for (int o = 8; o > 0; o >>= 1) v += __shfl_down(v, o);
            if (lane == 0) sred[0] = v + 1e-10f;
        }
        __syncthreads();
        const float integral = sred[0];
#pragma unroll
        for (int k = 0; k < F_ / 1024; ++k) {
            int j = tid + k * 1024;
            pb[j] = pb[j] / integral;
        }
    }
}

extern "C" void kernel_launch(void* const* d_in, const int* in_sizes, int n_in,
                              void* d_out, int out_size, void* d_ws, size_t ws_size,
                              hipStream_t stream) {
    const float* t     = (const float*)d_in[0];
    const float* y     = (const float*)d_in[1];
    const float* mask  = (const float*)d_in[2];
    const float* freqs = (const float*)d_in[3];
    float* out = (float*)d_out;
    unsigned* cnt = (unsigned*)d_ws;

    hipMemsetAsync(d_ws, 0, 16 * sizeof(unsigned), stream);  // zero per-batch counters

    dim3 grid1(F_ / FPB, B_);   // 32 x 16 = 512 blocks x 1024 threads
    ls_power_kernel<<<grid1, 1024, 0, stream>>>(t, y, mask, freqs, out, cnt);
}